// Round 18
// baseline (802.186 us; speedup 1.0000x reference)
//
#include <hip/hip_runtime.h>
#include <hip/hip_fp8.h>

#define C_ 512
#define T_ 2048
#define N_TOK 16384
#define K_CB 4096

typedef __attribute__((ext_vector_type(16))) float f32x16;
typedef __attribute__((ext_vector_type(2))) long long2v;

static __device__ __forceinline__ unsigned char f2fp8(float f) {
    __hip_fp8_e4m3 v(f);                 // OCP e4m3, RNE + saturate
    return (unsigned char)v.__x;
}

static __device__ __forceinline__ float fsqrt(float x) {
#if __has_builtin(__builtin_amdgcn_sqrtf)
    return __builtin_amdgcn_sqrtf(x);    // raw v_sqrt_f32 (1-2 ulp), no Newton fixup
#else
    float r; asm volatile("v_sqrt_f32 %0, %1" : "=v"(r) : "v"(x)); return r;
#endif
}

typedef const __attribute__((address_space(1))) void* gas_t;
typedef __attribute__((address_space(3))) void* las_t;
static __device__ __forceinline__ void stage16(const void* g, void* l) {
    __builtin_amdgcn_global_load_lds((gas_t)g, (las_t)l, 16, 0, 0);
}

// ---------------- Kernel 1 (merged): blocks 0-511 = student transpose/stats; 512-1535 = codebook
__global__ __launch_bounds__(256) void k1_all(
    const float* __restrict__ student,   // (B,C,T) fp32
    const int* __restrict__ codes,       // (B,T) int32
    const float* __restrict__ codebook,  // (K,C) fp32
    unsigned char* __restrict__ A8,      // (N,C) fp8 out
    unsigned char* __restrict__ B8f,     // fragment-linear fp8 codebook out
    float* __restrict__ cbnorm,
    float* __restrict__ xnorm, float* __restrict__ dtg2)
{
    int tid = threadIdx.x;
    if (blockIdx.x >= 512) {
        // ---------------- codebook -> fragment-linear fp8 + row norms ----------------
        int lane = tid & 63;
        int w = tid >> 6;
        int row = (blockIdx.x - 512) * 4 + w;
        const float* src = codebook + (size_t)row * C_ + lane * 8;
        float4 v0 = *(const float4*)(src);
        float4 v1 = *(const float4*)(src + 4);
        float s = v0.x*v0.x + v0.y*v0.y + v0.z*v0.z + v0.w*v0.w
                + v1.x*v1.x + v1.y*v1.y + v1.z*v1.z + v1.w*v1.w;
        unsigned lo = (unsigned)f2fp8(v0.x) | ((unsigned)f2fp8(v0.y) << 8)
                    | ((unsigned)f2fp8(v0.z) << 16) | ((unsigned)f2fp8(v0.w) << 24);
        unsigned hi = (unsigned)f2fp8(v1.x) | ((unsigned)f2fp8(v1.y) << 8)
                    | ((unsigned)f2fp8(v1.z) << 16) | ((unsigned)f2fp8(v1.w) << 24);
        size_t off = (size_t)(row >> 5) * 16384 + (size_t)(lane >> 1) * 512
                   + (size_t)(lane & 1) * 256 + (size_t)(row & 31) * 8;
        *(uint2*)(B8f + off) = make_uint2(lo, hi);
#pragma unroll
        for (int m = 1; m < 64; m <<= 1) s += __shfl_xor(s, m);
        if (lane == 0) cbnorm[row] = s;
        return;
    }
    // ---------------- student transpose (B,C,T)->(N,C) fp8 + per-token partial stats ----------
    __shared__ float tile[64][65];
    __shared__ int lcodes[64];
    int tnum  = blockIdx.x >> 1;
    int chalf = blockIdx.x & 1;
    int b  = tnum >> 5;
    int t0 = (tnum & 31) << 6;
    int cbase = chalf << 8;             // 0 or 256
    int cx = tid & 63;                  // lane
    int q  = tid >> 6;                  // wave
    if (tid < 64) lcodes[tid] = codes[b * T_ + t0 + tid];
    __syncthreads();
    float ax2[16], ad2[16];
#pragma unroll
    for (int p = 0; p < 16; ++p) { ax2[p] = 0.f; ad2[p] = 0.f; }
    for (int c0 = cbase; c0 < cbase + 256; c0 += 64) {
        // vectorized tile fill: wave q covers channels [q*16, q*16+16), float4 along T
#pragma unroll
        for (int i = 0; i < 4; ++i) {
            int ch = q * 16 + i * 4 + (cx >> 4);
            int tq = cx & 15;
            float4 v = *(const float4*)(student + (size_t)b * (C_ * T_)
                                        + (size_t)(c0 + ch) * T_ + t0 + tq * 4);
            tile[ch][tq * 4 + 0] = v.x;
            tile[ch][tq * 4 + 1] = v.y;
            tile[ch][tq * 4 + 2] = v.z;
            tile[ch][tq * 4 + 3] = v.w;
        }
        __syncthreads();
#pragma unroll
        for (int p = 0; p < 16; ++p) {
            int ty = p * 4 + q;
            float x = tile[cx][ty];
            int n = b * T_ + t0 + ty;
            A8[(size_t)n * C_ + c0 + cx] = f2fp8(x);
            ax2[p] += x * x;
            float cb = codebook[(size_t)lcodes[ty] * C_ + c0 + cx];
            float d = x - cb;
            ad2[p] += d * d;
        }
        __syncthreads();
    }
#pragma unroll
    for (int p = 0; p < 16; ++p) {
        float sx = ax2[p], sd = ad2[p];
#pragma unroll
        for (int m = 1; m < 64; m <<= 1) {
            sx += __shfl_xor(sx, m);
            sd += __shfl_xor(sd, m);
        }
        if (cx == 0) {
            int n = b * T_ + t0 + p * 4 + q;
            atomicAdd(&xnorm[n], sx);
            atomicAdd(&dtg2[n], sd);
        }
    }
}

// ---------------- Kernel 2: staggered half-GEMM pipeline: GEMM(accX) || epilogue(accY) ---------
// grid = 1024 (256 row-strips x 4 col-quarters, XCD-chunked); block = 512 (8 waves, 1x8).
// Per cc, two half-GEMMs (rows 0-31 -> acc0, rows 32-63 -> acc1; full K each, 32 MFMA).
// The epilogue of the OTHER acc's finished cc is interleaved at 4-MFMA/4-element granularity:
// epilogue VALU/trans executes under the matrix-pipe shadow. Only 2 acc sets (32 AGPRs) --
// R16's register profile, no spill. B fragments loaded twice per cc (L2-resident, cheap).
__global__ __launch_bounds__(512, 4) void k2_main(
    const unsigned char* __restrict__ A8,
    const unsigned char* __restrict__ B8f,
    const float* __restrict__ xnorm,
    const float* __restrict__ dtg2,
    const float* __restrict__ cbnorm,
    float* __restrict__ s_sum,
    unsigned* __restrict__ minpack)
{
    __shared__ __align__(16) unsigned char aL[32768];      // A: [rt2][j16][lane64][16B]
    __shared__ __align__(16) float cbL[1024];              // cbnorm for this col-quarter
    int tid = threadIdx.x;
    int lane = tid & 63;
    int wc = tid >> 6;                   // 0..7: wave owns cols [wc*32, wc*32+32) of each cc
    int l31 = lane & 31;
    int kh = lane >> 5;

    int orig = blockIdx.x;               // 1024 = 8 XCD x 128
    int swz = (orig & 7) * 128 + (orig >> 3);
    int strip = swz >> 2;                // 0..255
    int cq = swz & 3;                    // col quarter 0..3
    int row0 = strip * 64;
    int cbase = cq * 1024;

    // ---- stage A once, reg->LDS, m-pair fragment-linear layout (R14-verified) ----
#pragma unroll
    for (int i = 0; i < 4; ++i) {
        int li = i * 512 + tid;
        int R = li >> 5, M = li & 31;
        uint4 v = *(const uint4*)(A8 + (size_t)(row0 + R) * C_ + M * 16);
        char* base = (char*)aL + (R >> 5) * 16384 + (M >> 1) * 1024 + (M & 1) * 8;
        *(uint2*)(base + (R & 31) * 16)       = make_uint2(v.x, v.y);   // kh = 0
        *(uint2*)(base + 512 + (R & 31) * 16) = make_uint2(v.z, v.w);   // kh = 1
    }
    // ---- stage cbnorm quarter once ----
    if (tid < 256)
        stage16((const char*)cbnorm + (size_t)cbase * 4 + tid * 16, (char*)cbL + tid * 16);
    __syncthreads();                     // the ONLY barrier

    int myrow0 = row0 + l31, myrow1 = row0 + 32 + l31;
    float xn0 = xnorm[myrow0], xn1 = xnorm[myrow1];
    float dt0 = fsqrt(dtg2[myrow0]), dt1 = fsqrt(dtg2[myrow1]);
    float sv0 = 0.f, sv1 = 0.f;
    unsigned km0 = 0xFFFFFFFFu, km1 = 0xFFFFFFFFu;

    f32x16 acc0, acc1;                   // rows 0-31 / rows 32-63 (AGPRs) -- only TWO sets
#pragma unroll
    for (int r = 0; r < 16; ++r) { acc0[r] = 0.f; acc1[r] = 0.f; }

    const char* aBase = (const char*)aL + lane * 16;   // single addr reg; rest is imm offsets
    const unsigned char* gB = B8f + (size_t)(cq * 32 + wc) * 16384 + lane * 8;
    int wlc = wc * 32 + 4 * kh;          // lane's col base within a cc (local)

    // 2 MFMA for slot j into ACC (compile-time j)
#define GJ(ACC, AOFS, j)                                                       \
    { long bE = *(const long*)(gB + (j) * 1024);                               \
      long bO = *(const long*)(gB + (j) * 1024 + 512);                         \
      long2v av = *(const long2v*)(aBase + (AOFS) + (j) * 1024);               \
      ACC = __builtin_amdgcn_mfma_f32_32x32x16_fp8_fp8(bE, av[0], ACC, 0, 0, 0); \
      ACC = __builtin_amdgcn_mfma_f32_32x32x16_fp8_fp8(bO, av[1], ACC, 0, 0, 0); }

    // epilogue of ONE element (compile-time j) of E at runtime col base elc0; re-zeros E[j]
#define EPI1(E, j, XN, DT, SV, KM, elc0)                                       \
    { int lc = (elc0) + ((j) & 3) + 8 * ((j) >> 2);                            \
      float cbn = cbL[lc];                                                     \
      float d2 = fmaxf(fmaf(-2.f, E[j], XN) + cbn, 0.f);                       \
      SV += __expf(DT - fsqrt(d2));                                            \
      KM = min(KM, (__float_as_uint(d2) & 0xFFFFF000u) | (unsigned)(cbase + lc)); \
      E[j] = 0.f; }

    // 4 GEMM slots then 4 epilogue elements (bounds load-hoisting to R14's unroll-4 profile)
#define GRP4(ACC, AOFS, J0, DOEPI, E, XN, DT, SV, KM, elc0)                    \
    GJ(ACC, AOFS, (J0)+0) GJ(ACC, AOFS, (J0)+1)                                \
    GJ(ACC, AOFS, (J0)+2) GJ(ACC, AOFS, (J0)+3)                                \
    if (DOEPI) { EPI1(E, (J0)+0, XN, DT, SV, KM, elc0)                         \
                 EPI1(E, (J0)+1, XN, DT, SV, KM, elc0)                         \
                 EPI1(E, (J0)+2, XN, DT, SV, KM, elc0)                         \
                 EPI1(E, (J0)+3, XN, DT, SV, KM, elc0) }

#define HALF(ACC, AOFS, DOEPI, E, XN, DT, SV, KM, elc0)                        \
    GRP4(ACC, AOFS, 0,  DOEPI, E, XN, DT, SV, KM, elc0)                        \
    GRP4(ACC, AOFS, 4,  DOEPI, E, XN, DT, SV, KM, elc0)                        \
    GRP4(ACC, AOFS, 8,  DOEPI, E, XN, DT, SV, KM, elc0)                        \
    GRP4(ACC, AOFS, 12, DOEPI, E, XN, DT, SV, KM, elc0)

    int elc = wlc;                       // col base (local) of the cc being epilogued
    // cc0
    HALF(acc0, 0,     0, acc1, xn1, dt1, sv1, km1, elc)   // GEMM rows0 (no epi yet)
    HALF(acc1, 16384, 1, acc0, xn0, dt0, sv0, km0, elc)   // GEMM rows1 || epi acc0@cc0
    gB += 8 * 16384;
    // cc1
    HALF(acc0, 0,     1, acc1, xn1, dt1, sv1, km1, elc)   // GEMM rows0 || epi acc1@cc0
    elc += 256;
    HALF(acc1, 16384, 1, acc0, xn0, dt0, sv0, km0, elc)   // GEMM rows1 || epi acc0@cc1
    gB += 8 * 16384;
    // cc2
    HALF(acc0, 0,     1, acc1, xn1, dt1, sv1, km1, elc)   // || epi acc1@cc1
    elc += 256;
    HALF(acc1, 16384, 1, acc0, xn0, dt0, sv0, km0, elc)   // || epi acc0@cc2
    gB += 8 * 16384;
    // cc3
    HALF(acc0, 0,     1, acc1, xn1, dt1, sv1, km1, elc)   // || epi acc1@cc2
    elc += 256;
    HALF(acc1, 16384, 1, acc0, xn0, dt0, sv0, km0, elc)   // || epi acc0@cc3
    // tail: epilogue of acc1@cc3
    EPI1(acc1, 0, xn1, dt1, sv1, km1, elc)  EPI1(acc1, 1, xn1, dt1, sv1, km1, elc)
    EPI1(acc1, 2, xn1, dt1, sv1, km1, elc)  EPI1(acc1, 3, xn1, dt1, sv1, km1, elc)
    EPI1(acc1, 4, xn1, dt1, sv1, km1, elc)  EPI1(acc1, 5, xn1, dt1, sv1, km1, elc)
    EPI1(acc1, 6, xn1, dt1, sv1, km1, elc)  EPI1(acc1, 7, xn1, dt1, sv1, km1, elc)
    EPI1(acc1, 8, xn1, dt1, sv1, km1, elc)  EPI1(acc1, 9, xn1, dt1, sv1, km1, elc)
    EPI1(acc1, 10, xn1, dt1, sv1, km1, elc) EPI1(acc1, 11, xn1, dt1, sv1, km1, elc)
    EPI1(acc1, 12, xn1, dt1, sv1, km1, elc) EPI1(acc1, 13, xn1, dt1, sv1, km1, elc)
    EPI1(acc1, 14, xn1, dt1, sv1, km1, elc) EPI1(acc1, 15, xn1, dt1, sv1, km1, elc)
#undef HALF
#undef GRP4
#undef EPI1
#undef GJ

    // merge k-halves (lane vs lane+32: same student rows, disjoint cb-col quads)
    sv0 += __shfl_xor(sv0, 32);
    sv1 += __shfl_xor(sv1, 32);
    km0 = min(km0, (unsigned)__shfl_xor((int)km0, 32));
    km1 = min(km1, (unsigned)__shfl_xor((int)km1, 32));
    if (lane < 32) {
        atomicAdd(&s_sum[myrow0], sv0);
        atomicMin(&minpack[myrow0], km0);
        atomicAdd(&s_sum[myrow1], sv1);
        atomicMin(&minpack[myrow1], km1);
    }
}

// ---------------- Kernel 3a: per-token CE/accuracy/emb-loss/target-dist reduce ----------------
__global__ __launch_bounds__(256) void k3a(
    const float* __restrict__ s_sum,
    const unsigned* __restrict__ minpack,
    const int* __restrict__ codes,
    const float* __restrict__ dtg2,
    float* __restrict__ accum)
{
    __shared__ float w0[4], w1[4], w2[4], w3[4];
    int tid = threadIdx.x;
    int n = blockIdx.x * 256 + tid;
    float ce = logf(s_sum[n]);           // = d_t + lse(-d) = per-token CE
    unsigned pred = minpack[n] & 0xFFFu; // col id in the low 12 bits
    float ok = (pred == (unsigned)codes[n]) ? 1.f : 0.f;
    float sq = dtg2[n];
    float td = sqrtf(sq);
#pragma unroll
    for (int m = 1; m < 64; m <<= 1) {
        ce += __shfl_xor(ce, m);
        ok += __shfl_xor(ok, m);
        sq += __shfl_xor(sq, m);
        td += __shfl_xor(td, m);
    }
    int lane = tid & 63, w = tid >> 6;
    if (lane == 0) { w0[w] = ce; w1[w] = ok; w2[w] = sq; w3[w] = td; }
    __syncthreads();
    if (tid == 0) {
        atomicAdd(&accum[0], w0[0] + w0[1] + w0[2] + w0[3]);
        atomicAdd(&accum[1], w1[0] + w1[1] + w1[2] + w1[3]);
        atomicAdd(&accum[2], w2[0] + w2[1] + w2[2] + w2[3]);
        atomicAdd(&accum[3], w3[0] + w3[1] + w3[2] + w3[3]);
    }
}

// ---------------- Kernel 3b: finalize 5 outputs ----------------
__global__ void k3b(const float* __restrict__ accum, float* __restrict__ out)
{
    if (threadIdx.x == 0 && blockIdx.x == 0) {
        float ce   = accum[0] / (float)N_TOK;
        float accy = accum[1] / (float)N_TOK;
        float emb  = accum[2] / ((float)N_TOK * (float)C_);
        float td   = accum[3] / (float)N_TOK;
        out[0] = emb + ce;   // total_loss (EMB_W=CE_W=1)
        out[1] = emb;        // emb_to_codebook_loss
        out[2] = ce;         // ce_loss
        out[3] = accy;       // token_accuracy
        out[4] = td;         // emb_to_target_dist
    }
}

extern "C" void kernel_launch(void* const* d_in, const int* in_sizes, int n_in,
                              void* d_out, int out_size, void* d_ws, size_t ws_size,
                              hipStream_t stream)
{
    const float* student  = (const float*)d_in[0];
    const int*   codes    = (const int*)d_in[1];
    const float* codebook = (const float*)d_in[2];
    // d_in[3] distance_matrix is unused by the reference.
    float* out = (float*)d_out;

    char* ws = (char*)d_ws;
    unsigned char* A8     = (unsigned char*)(ws);                  // 8 MiB
    unsigned char* B8f    = (unsigned char*)(ws + 8388608);        // 2 MiB (fragment-linear)
    float* xnorm          = (float*)(ws + 10485760);               // 64 KiB  ─┐
    float* dtg2           = (float*)(ws + 10551296);               // 64 KiB   │ one zero-memset
    float* s_sum          = (float*)(ws + 10616832);               // 64 KiB   │
    float* accum          = (float*)(ws + 10682368);               // 64 B    ─┘
    unsigned* minpack     = (unsigned*)(ws + 10682624);            // 64 KiB (0xFF memset)
    float* cbnorm         = (float*)(ws + 10748160);               // 16 KiB (fully written by k1)

    hipMemsetAsync(ws + 10485760, 0, 196672, stream);              // xnorm+dtg2+s_sum+accum
    hipMemsetAsync(ws + 10682624, 0xFF, 65536, stream);            // minpack

    // merged prep: blocks 0-511 student transpose/stats, 512-1535 codebook conversion
    hipLaunchKernelGGL(k1_all, dim3(1536), dim3(256), 0, stream,
                       student, codes, codebook, A8, B8f, cbnorm, xnorm, dtg2);
    hipLaunchKernelGGL(k2_main, dim3(1024), dim3(512), 0, stream,
                       A8, B8f, xnorm, dtg2, cbnorm, s_sum, minpack);
    hipLaunchKernelGGL(k3a, dim3(64), dim3(256), 0, stream,
                       s_sum, minpack, codes, dtg2, accum);
    hipLaunchKernelGGL(k3b, dim3(1), dim3(64), 0, stream, accum, out);
}

// Round 19
// 261.189 us; speedup vs baseline: 3.0713x; 3.0713x over previous
//
#include <hip/hip_runtime.h>
#include <hip/hip_fp8.h>

#define C_ 512
#define T_ 2048
#define N_TOK 16384
#define K_CB 4096

typedef __attribute__((ext_vector_type(16))) float f32x16;
typedef __attribute__((ext_vector_type(2))) long long2v;

static __device__ __forceinline__ unsigned char f2fp8(float f) {
    __hip_fp8_e4m3 v(f);                 // OCP e4m3, RNE + saturate
    return (unsigned char)v.__x;
}

static __device__ __forceinline__ float fsqrt(float x) {
#if __has_builtin(__builtin_amdgcn_sqrtf)
    return __builtin_amdgcn_sqrtf(x);    // raw v_sqrt_f32 (1-2 ulp), no Newton fixup
#else
    float r; asm volatile("v_sqrt_f32 %0, %1" : "=v"(r) : "v"(x)); return r;
#endif
}

typedef const __attribute__((address_space(1))) void* gas_t;
typedef __attribute__((address_space(3))) void* las_t;
static __device__ __forceinline__ void stage16(const void* g, void* l) {
    __builtin_amdgcn_global_load_lds((gas_t)g, (las_t)l, 16, 0, 0);
}

// ---------------- Kernel 1 (merged): blocks 0-511 = student transpose/stats; 512-1535 = codebook
__global__ __launch_bounds__(256) void k1_all(
    const float* __restrict__ student,   // (B,C,T) fp32
    const int* __restrict__ codes,       // (B,T) int32
    const float* __restrict__ codebook,  // (K,C) fp32
    unsigned char* __restrict__ A8,      // (N,C) fp8 out
    unsigned char* __restrict__ B8f,     // fragment-linear fp8 codebook out
    float* __restrict__ cbnorm,
    float* __restrict__ xnorm, float* __restrict__ dtg2)
{
    int tid = threadIdx.x;
    if (blockIdx.x >= 512) {
        // ---------------- codebook -> fragment-linear fp8 + row norms ----------------
        int lane = tid & 63;
        int w = tid >> 6;
        int row = (blockIdx.x - 512) * 4 + w;
        const float* src = codebook + (size_t)row * C_ + lane * 8;
        float4 v0 = *(const float4*)(src);
        float4 v1 = *(const float4*)(src + 4);
        float s = v0.x*v0.x + v0.y*v0.y + v0.z*v0.z + v0.w*v0.w
                + v1.x*v1.x + v1.y*v1.y + v1.z*v1.z + v1.w*v1.w;
        unsigned lo = (unsigned)f2fp8(v0.x) | ((unsigned)f2fp8(v0.y) << 8)
                    | ((unsigned)f2fp8(v0.z) << 16) | ((unsigned)f2fp8(v0.w) << 24);
        unsigned hi = (unsigned)f2fp8(v1.x) | ((unsigned)f2fp8(v1.y) << 8)
                    | ((unsigned)f2fp8(v1.z) << 16) | ((unsigned)f2fp8(v1.w) << 24);
        size_t off = (size_t)(row >> 5) * 16384 + (size_t)(lane >> 1) * 512
                   + (size_t)(lane & 1) * 256 + (size_t)(row & 31) * 8;
        *(uint2*)(B8f + off) = make_uint2(lo, hi);
#pragma unroll
        for (int m = 1; m < 64; m <<= 1) s += __shfl_xor(s, m);
        if (lane == 0) cbnorm[row] = s;
        return;
    }
    // ---------------- student transpose (B,C,T)->(N,C) fp8 + per-token partial stats ----------
    __shared__ float tile[64][65];
    __shared__ int lcodes[64];
    int tnum  = blockIdx.x >> 1;
    int chalf = blockIdx.x & 1;
    int b  = tnum >> 5;
    int t0 = (tnum & 31) << 6;
    int cbase = chalf << 8;             // 0 or 256
    int cx = tid & 63;                  // lane
    int q  = tid >> 6;                  // wave
    if (tid < 64) lcodes[tid] = codes[b * T_ + t0 + tid];
    __syncthreads();
    float ax2[16], ad2[16];
#pragma unroll
    for (int p = 0; p < 16; ++p) { ax2[p] = 0.f; ad2[p] = 0.f; }
    for (int c0 = cbase; c0 < cbase + 256; c0 += 64) {
        // vectorized tile fill: wave q covers channels [q*16, q*16+16), float4 along T
#pragma unroll
        for (int i = 0; i < 4; ++i) {
            int ch = q * 16 + i * 4 + (cx >> 4);
            int tq = cx & 15;
            float4 v = *(const float4*)(student + (size_t)b * (C_ * T_)
                                        + (size_t)(c0 + ch) * T_ + t0 + tq * 4);
            tile[ch][tq * 4 + 0] = v.x;
            tile[ch][tq * 4 + 1] = v.y;
            tile[ch][tq * 4 + 2] = v.z;
            tile[ch][tq * 4 + 3] = v.w;
        }
        __syncthreads();
#pragma unroll
        for (int p = 0; p < 16; ++p) {
            int ty = p * 4 + q;
            float x = tile[cx][ty];
            int n = b * T_ + t0 + ty;
            A8[(size_t)n * C_ + c0 + cx] = f2fp8(x);
            ax2[p] += x * x;
            float cb = codebook[(size_t)lcodes[ty] * C_ + c0 + cx];
            float d = x - cb;
            ad2[p] += d * d;
        }
        __syncthreads();
    }
#pragma unroll
    for (int p = 0; p < 16; ++p) {
        float sx = ax2[p], sd = ad2[p];
#pragma unroll
        for (int m = 1; m < 64; m <<= 1) {
            sx += __shfl_xor(sx, m);
            sd += __shfl_xor(sd, m);
        }
        if (cx == 0) {
            int n = b * T_ + t0 + p * 4 + q;
            atomicAdd(&xnorm[n], sx);
            atomicAdd(&dtg2[n], sd);
        }
    }
}

// ---------------- Kernel 2: ping-pong tile pipeline, WAR-free: GEMM(X) || EPI(Y!=X) -----------
// grid = 1024 (256 row-strips x 4 col-quarters, XCD-chunked); block = 512 (8 waves = 2 row-halves
// x 4 col-groups: wave = 32 rows x 64 cols = 2 col-tiles of 32). Per tile: 32 MFMA into ONE
// f32x16. P/Q ping-pong across tiles; epilogue placed one-behind in source so each EPI(X) sits
// after a GEMM(Y!=X) -> scheduler may interleave EPI VALU/trans into GEMM's MFMA dep-stalls,
// and every acc is fully epilogued before being rewritten (WAR satisfied in source order).
// Only 2 acc sets (32 AGPR) + R16-style unroll loops: the no-spill register profile.
__global__ __launch_bounds__(512, 4) void k2_main(
    const unsigned char* __restrict__ A8,
    const unsigned char* __restrict__ B8f,
    const float* __restrict__ xnorm,
    const float* __restrict__ dtg2,
    const float* __restrict__ cbnorm,
    float* __restrict__ s_sum,
    unsigned* __restrict__ minpack)
{
    __shared__ __align__(16) unsigned char aL[32768];      // A: [rh2][j16][lane64][16B]
    __shared__ __align__(16) float cbL[1024];              // cbnorm for this col-quarter
    int tid = threadIdx.x;
    int lane = tid & 63;
    int w8 = tid >> 6;                   // 0..7
    int rh = w8 >> 2;                    // row half 0/1
    int wc = w8 & 3;                     // col group 0..3 (64 cols each per cc)
    int l31 = lane & 31;
    int kh = lane >> 5;

    int orig = blockIdx.x;               // 1024 = 8 XCD x 128
    int swz = (orig & 7) * 128 + (orig >> 3);
    int strip = swz >> 2;                // 0..255
    int cq = swz & 3;                    // col quarter 0..3
    int row0 = strip * 64;
    int cbase = cq * 1024;

    // ---- stage A once, reg->LDS, m-pair fragment-linear layout (R14-verified) ----
#pragma unroll
    for (int i = 0; i < 4; ++i) {
        int li = i * 512 + tid;
        int R = li >> 5, M = li & 31;
        uint4 v = *(const uint4*)(A8 + (size_t)(row0 + R) * C_ + M * 16);
        char* base = (char*)aL + (R >> 5) * 16384 + (M >> 1) * 1024 + (M & 1) * 8;
        *(uint2*)(base + (R & 31) * 16)       = make_uint2(v.x, v.y);   // kh = 0
        *(uint2*)(base + 512 + (R & 31) * 16) = make_uint2(v.z, v.w);   // kh = 1
    }
    // ---- stage cbnorm quarter once ----
    if (tid < 256)
        stage16((const char*)cbnorm + (size_t)cbase * 4 + tid * 16, (char*)cbL + tid * 16);
    __syncthreads();                     // the ONLY barrier

    int myrow = row0 + rh * 32 + l31;
    float xn = xnorm[myrow];
    float dt = fsqrt(dtg2[myrow]);
    float sv = 0.f;
    unsigned km = 0xFFFFFFFFu;

    f32x16 P, Q;                         // two acc sets (AGPRs), ping-pong across tiles
#pragma unroll
    for (int r = 0; r < 16; ++r) { P[r] = 0.f; Q[r] = 0.f; }

    const char* aBase = (const char*)aL + rh * 16384 + lane * 16;  // 1 addr reg + imm offsets
    const unsigned char* gB0 = B8f + (size_t)(cq * 32 + wc * 2) * 16384 + lane * 8;
    int tbBase = wc * 64 + 4 * kh;       // lane's col base within quarter (runtime part)

    // GEMM one 32x32 col-tile into ACC; GOFS = (cc*8 + t)*16384 (compile-time)
#define GEMM_TILE(ACC, GOFS)                                                   \
    { _Pragma("unroll")                                                        \
      for (int j = 0; j < 16; ++j) {                                           \
          long bE = *(const long*)(gB0 + (GOFS) + j * 1024);                   \
          long bO = *(const long*)(gB0 + (GOFS) + j * 1024 + 512);             \
          long2v av = *(const long2v*)(aBase + j * 1024);                      \
          ACC = __builtin_amdgcn_mfma_f32_32x32x16_fp8_fp8(bE, av[0], ACC, 0, 0, 0); \
          ACC = __builtin_amdgcn_mfma_f32_32x32x16_fp8_fp8(bO, av[1], ACC, 0, 0, 0); \
      } }

    // epilogue of acc E for the tile at local col base (tbBase + TOFS); re-zeros E
#define EPI_TILE(E, TOFS)                                                      \
    { _Pragma("unroll")                                                        \
      for (int j = 0; j < 16; ++j) {                                           \
          int lc = tbBase + (TOFS) + (j & 3) + 8 * (j >> 2);                   \
          float cbn = cbL[lc];                                                 \
          float d2 = fmaxf(fmaf(-2.f, E[j], xn) + cbn, 0.f);                   \
          sv += __expf(dt - fsqrt(d2));                                        \
          km = min(km, (__float_as_uint(d2) & 0xFFFFF000u) | (unsigned)(cbase + lc)); \
          E[j] = 0.f;                                                          \
      } }

    GEMM_TILE(P, 0 * 16384)              // cc0 t0 -> P
    GEMM_TILE(Q, 1 * 16384)              // cc0 t1 -> Q
    EPI_TILE(P, 0)                       // epi cc0t0   (interleaves with G above / below)
    GEMM_TILE(P, 8 * 16384)              // cc1 t0 -> P
    EPI_TILE(Q, 32)                      // epi cc0t1 || G(cc1t0)
    GEMM_TILE(Q, 9 * 16384)              // cc1 t1 -> Q
    EPI_TILE(P, 256)                     // epi cc1t0 || G(cc1t1)
    GEMM_TILE(P, 16 * 16384)             // cc2 t0 -> P
    EPI_TILE(Q, 256 + 32)                // epi cc1t1 || G(cc2t0)
    GEMM_TILE(Q, 17 * 16384)             // cc2 t1 -> Q
    EPI_TILE(P, 512)                     // epi cc2t0 || G(cc2t1)
    GEMM_TILE(P, 24 * 16384)             // cc3 t0 -> P
    EPI_TILE(Q, 512 + 32)                // epi cc2t1 || G(cc3t0)
    GEMM_TILE(Q, 25 * 16384)             // cc3 t1 -> Q
    EPI_TILE(P, 768)                     // epi cc3t0 || G(cc3t1)
    EPI_TILE(Q, 768 + 32)                // tail: epi cc3t1
#undef GEMM_TILE
#undef EPI_TILE

    // merge k-halves (lane vs lane+32: same student row, disjoint cb-col quads)
    sv += __shfl_xor(sv, 32);
    km = min(km, (unsigned)__shfl_xor((int)km, 32));
    if (lane < 32) {
        atomicAdd(&s_sum[myrow], sv);
        atomicMin(&minpack[myrow], km);
    }
}

// ---------------- Kernel 3a: per-token CE/accuracy/emb-loss/target-dist reduce ----------------
__global__ __launch_bounds__(256) void k3a(
    const float* __restrict__ s_sum,
    const unsigned* __restrict__ minpack,
    const int* __restrict__ codes,
    const float* __restrict__ dtg2,
    float* __restrict__ accum)
{
    __shared__ float w0[4], w1[4], w2[4], w3[4];
    int tid = threadIdx.x;
    int n = blockIdx.x * 256 + tid;
    float ce = logf(s_sum[n]);           // = d_t + lse(-d) = per-token CE
    unsigned pred = minpack[n] & 0xFFFu; // col id in the low 12 bits
    float ok = (pred == (unsigned)codes[n]) ? 1.f : 0.f;
    float sq = dtg2[n];
    float td = sqrtf(sq);
#pragma unroll
    for (int m = 1; m < 64; m <<= 1) {
        ce += __shfl_xor(ce, m);
        ok += __shfl_xor(ok, m);
        sq += __shfl_xor(sq, m);
        td += __shfl_xor(td, m);
    }
    int lane = tid & 63, w = tid >> 6;
    if (lane == 0) { w0[w] = ce; w1[w] = ok; w2[w] = sq; w3[w] = td; }
    __syncthreads();
    if (tid == 0) {
        atomicAdd(&accum[0], w0[0] + w0[1] + w0[2] + w0[3]);
        atomicAdd(&accum[1], w1[0] + w1[1] + w1[2] + w1[3]);
        atomicAdd(&accum[2], w2[0] + w2[1] + w2[2] + w2[3]);
        atomicAdd(&accum[3], w3[0] + w3[1] + w3[2] + w3[3]);
    }
}

// ---------------- Kernel 3b: finalize 5 outputs ----------------
__global__ void k3b(const float* __restrict__ accum, float* __restrict__ out)
{
    if (threadIdx.x == 0 && blockIdx.x == 0) {
        float ce   = accum[0] / (float)N_TOK;
        float accy = accum[1] / (float)N_TOK;
        float emb  = accum[2] / ((float)N_TOK * (float)C_);
        float td   = accum[3] / (float)N_TOK;
        out[0] = emb + ce;   // total_loss (EMB_W=CE_W=1)
        out[1] = emb;        // emb_to_codebook_loss
        out[2] = ce;         // ce_loss
        out[3] = accy;       // token_accuracy
        out[4] = td;         // emb_to_target_dist
    }
}

extern "C" void kernel_launch(void* const* d_in, const int* in_sizes, int n_in,
                              void* d_out, int out_size, void* d_ws, size_t ws_size,
                              hipStream_t stream)
{
    const float* student  = (const float*)d_in[0];
    const int*   codes    = (const int*)d_in[1];
    const float* codebook = (const float*)d_in[2];
    // d_in[3] distance_matrix is unused by the reference.
    float* out = (float*)d_out;

    char* ws = (char*)d_ws;
    unsigned char* A8     = (unsigned char*)(ws);                  // 8 MiB
    unsigned char* B8f    = (unsigned char*)(ws + 8388608);        // 2 MiB (fragment-linear)
    float* xnorm          = (float*)(ws + 10485760);               // 64 KiB  ─┐
    float* dtg2           = (float*)(ws + 10551296);               // 64 KiB   │ one zero-memset
    float* s_sum          = (float*)(ws + 10616832);               // 64 KiB   │
    float* accum          = (float*)(ws + 10682368);               // 64 B    ─┘
    unsigned* minpack     = (unsigned*)(ws + 10682624);            // 64 KiB (0xFF memset)
    float* cbnorm         = (float*)(ws + 10748160);               // 16 KiB (fully written by k1)

    hipMemsetAsync(ws + 10485760, 0, 196672, stream);              // xnorm+dtg2+s_sum+accum
    hipMemsetAsync(ws + 10682624, 0xFF, 65536, stream);            // minpack

    // merged prep: blocks 0-511 student transpose/stats, 512-1535 codebook conversion
    hipLaunchKernelGGL(k1_all, dim3(1536), dim3(256), 0, stream,
                       student, codes, codebook, A8, B8f, cbnorm, xnorm, dtg2);
    hipLaunchKernelGGL(k2_main, dim3(1024), dim3(512), 0, stream,
                       A8, B8f, xnorm, dtg2, cbnorm, s_sum, minpack);
    hipLaunchKernelGGL(k3a, dim3(64), dim3(256), 0, stream,
                       s_sum, minpack, codes, dtg2, accum);
    hipLaunchKernelGGL(k3b, dim3(1), dim3(64), 0, stream, accum, out);
}

// Round 20
// 106.670 us; speedup vs baseline: 7.5203x; 2.4486x over previous
//
#include <hip/hip_runtime.h>
#include <hip/hip_fp8.h>

#define C_ 512
#define T_ 2048
#define N_TOK 16384
#define K_CB 4096

typedef __attribute__((ext_vector_type(16))) float f32x16;
typedef __attribute__((ext_vector_type(2))) long long2v;

static __device__ __forceinline__ unsigned char f2fp8(float f) {
    __hip_fp8_e4m3 v(f);                 // OCP e4m3, RNE + saturate
    return (unsigned char)v.__x;
}

static __device__ __forceinline__ float fsqrt(float x) {
#if __has_builtin(__builtin_amdgcn_sqrtf)
    return __builtin_amdgcn_sqrtf(x);    // raw v_sqrt_f32 (1-2 ulp), no Newton fixup
#else
    float r; asm volatile("v_sqrt_f32 %0, %1" : "=v"(r) : "v"(x)); return r;
#endif
}

typedef const __attribute__((address_space(1))) void* gas_t;
typedef __attribute__((address_space(3))) void* las_t;
static __device__ __forceinline__ void stage16(const void* g, void* l) {
    __builtin_amdgcn_global_load_lds((gas_t)g, (las_t)l, 16, 0, 0);
}

// ---------------- Kernel 1 (merged): blocks 0-511 = student transpose/stats; 512-1535 = codebook
__global__ __launch_bounds__(256) void k1_all(
    const float* __restrict__ student,   // (B,C,T) fp32
    const int* __restrict__ codes,       // (B,T) int32
    const float* __restrict__ codebook,  // (K,C) fp32
    unsigned char* __restrict__ A8,      // (N,C) fp8 out
    unsigned char* __restrict__ B8f,     // fragment-linear fp8 codebook out
    float* __restrict__ cbnorm,
    float* __restrict__ xnorm, float* __restrict__ dtg2)
{
    int tid = threadIdx.x;
    if (blockIdx.x >= 512) {
        // ---------------- codebook -> fragment-linear fp8 + row norms ----------------
        int lane = tid & 63;
        int w = tid >> 6;
        int row = (blockIdx.x - 512) * 4 + w;
        const float* src = codebook + (size_t)row * C_ + lane * 8;
        float4 v0 = *(const float4*)(src);
        float4 v1 = *(const float4*)(src + 4);
        float s = v0.x*v0.x + v0.y*v0.y + v0.z*v0.z + v0.w*v0.w
                + v1.x*v1.x + v1.y*v1.y + v1.z*v1.z + v1.w*v1.w;
        unsigned lo = (unsigned)f2fp8(v0.x) | ((unsigned)f2fp8(v0.y) << 8)
                    | ((unsigned)f2fp8(v0.z) << 16) | ((unsigned)f2fp8(v0.w) << 24);
        unsigned hi = (unsigned)f2fp8(v1.x) | ((unsigned)f2fp8(v1.y) << 8)
                    | ((unsigned)f2fp8(v1.z) << 16) | ((unsigned)f2fp8(v1.w) << 24);
        size_t off = (size_t)(row >> 5) * 16384 + (size_t)(lane >> 1) * 512
                   + (size_t)(lane & 1) * 256 + (size_t)(row & 31) * 8;
        *(uint2*)(B8f + off) = make_uint2(lo, hi);
#pragma unroll
        for (int m = 1; m < 64; m <<= 1) s += __shfl_xor(s, m);
        if (lane == 0) cbnorm[row] = s;
        return;
    }
    // ---------------- student transpose (B,C,T)->(N,C) fp8 + per-token partial stats ----------
    __shared__ float tile[64][65];
    __shared__ int lcodes[64];
    int tnum  = blockIdx.x >> 1;
    int chalf = blockIdx.x & 1;
    int b  = tnum >> 5;
    int t0 = (tnum & 31) << 6;
    int cbase = chalf << 8;             // 0 or 256
    int cx = tid & 63;                  // lane
    int q  = tid >> 6;                  // wave
    if (tid < 64) lcodes[tid] = codes[b * T_ + t0 + tid];
    __syncthreads();
    float ax2[16], ad2[16];
#pragma unroll
    for (int p = 0; p < 16; ++p) { ax2[p] = 0.f; ad2[p] = 0.f; }
    for (int c0 = cbase; c0 < cbase + 256; c0 += 64) {
        // vectorized tile fill: wave q covers channels [q*16, q*16+16), float4 along T
#pragma unroll
        for (int i = 0; i < 4; ++i) {
            int ch = q * 16 + i * 4 + (cx >> 4);
            int tq = cx & 15;
            float4 v = *(const float4*)(student + (size_t)b * (C_ * T_)
                                        + (size_t)(c0 + ch) * T_ + t0 + tq * 4);
            tile[ch][tq * 4 + 0] = v.x;
            tile[ch][tq * 4 + 1] = v.y;
            tile[ch][tq * 4 + 2] = v.z;
            tile[ch][tq * 4 + 3] = v.w;
        }
        __syncthreads();
#pragma unroll
        for (int p = 0; p < 16; ++p) {
            int ty = p * 4 + q;
            float x = tile[cx][ty];
            int n = b * T_ + t0 + ty;
            A8[(size_t)n * C_ + c0 + cx] = f2fp8(x);
            ax2[p] += x * x;
            float cb = codebook[(size_t)lcodes[ty] * C_ + c0 + cx];
            float d = x - cb;
            ad2[p] += d * d;
        }
        __syncthreads();
    }
#pragma unroll
    for (int p = 0; p < 16; ++p) {
        float sx = ax2[p], sd = ad2[p];
#pragma unroll
        for (int m = 1; m < 64; m <<= 1) {
            sx += __shfl_xor(sx, m);
            sd += __shfl_xor(sd, m);
        }
        if (cx == 0) {
            int n = b * T_ + t0 + p * 4 + q;
            atomicAdd(&xnorm[n], sx);
            atomicAdd(&dtg2[n], sd);
        }
    }
}

// ---------------- Kernel 2: R16 base + SGPR-uniform B addressing + folded exp ----------------
// grid = 1024 (256 row-strips x 4 col-quarters, XCD-chunked); block = 512 (8 waves, 1x8).
// B base made provably wave-uniform via readfirstlane -> SGPR base + imm offsets, per-cc
// bump on the SALU pipe: kills per-load VALU address adds (the hidden half of VALUBusy).
// exp(dt-d) folded to e^dt * 2^(-d*log2e): one mul+exp per element, e^dt applied once.
__global__ __launch_bounds__(512, 4) void k2_main(
    const unsigned char* __restrict__ A8,
    const unsigned char* __restrict__ B8f,
    const float* __restrict__ xnorm,
    const float* __restrict__ dtg2,
    const float* __restrict__ cbnorm,
    float* __restrict__ s_sum,
    unsigned* __restrict__ minpack)
{
    __shared__ __align__(16) unsigned char aL[32768];      // A: [rt2][j16][lane64][16B]
    __shared__ __align__(16) float cbL[1024];              // cbnorm for this col-quarter
    int tid = threadIdx.x;
    int lane = tid & 63;
    int wc = tid >> 6;                   // 0..7: wave owns cols [wc*32, wc*32+32) of each cc
    int l31 = lane & 31;
    int kh = lane >> 5;

    int orig = blockIdx.x;               // 1024 = 8 XCD x 128
    int swz = (orig & 7) * 128 + (orig >> 3);
    int strip = swz >> 2;                // 0..255
    int cq = swz & 3;                    // col quarter 0..3
    int row0 = strip * 64;
    int cbase = cq * 1024;

    // ---- stage A once, reg->LDS, m-pair fragment-linear layout (R14-verified) ----
#pragma unroll
    for (int i = 0; i < 4; ++i) {
        int li = i * 512 + tid;
        int R = li >> 5, M = li & 31;
        uint4 v = *(const uint4*)(A8 + (size_t)(row0 + R) * C_ + M * 16);
        char* base = (char*)aL + (R >> 5) * 16384 + (M >> 1) * 1024 + (M & 1) * 8;
        *(uint2*)(base + (R & 31) * 16)       = make_uint2(v.x, v.y);   // kh = 0
        *(uint2*)(base + 512 + (R & 31) * 16) = make_uint2(v.z, v.w);   // kh = 1
    }
    // ---- stage cbnorm quarter once ----
    if (tid < 256)
        stage16((const char*)cbnorm + (size_t)cbase * 4 + tid * 16, (char*)cbL + tid * 16);
    __syncthreads();                     // the ONLY barrier

    int myrow0 = row0 + l31, myrow1 = row0 + 32 + l31;
    float xn0 = xnorm[myrow0], xn1 = xnorm[myrow1];
    float dt0 = fsqrt(dtg2[myrow0]), dt1 = fsqrt(dtg2[myrow1]);
    float sv0 = 0.f, sv1 = 0.f;
    unsigned km0 = 0xFFFFFFFFu, km1 = 0xFFFFFFFFu;

    f32x16 acc0, acc1;                   // rt = 0 / 1 (AGPRs)
#pragma unroll
    for (int r = 0; r < 16; ++r) { acc0[r] = 0.f; acc1[r] = 0.f; }

    const char* aBase = (const char*)aL + lane * 16;   // single LDS addr reg; imm offsets
    // wave-uniform B base (readfirstlane -> provably uniform -> SGPR base, SALU bumps)
    unsigned sOff = (unsigned)__builtin_amdgcn_readfirstlane((cq * 32 + wc) * 16384);
    const unsigned char* gB = B8f + sOff + lane * 8;
    int wlc = wc * 32 + 4 * kh;          // lane's col base within a cc (local)
    const float NL2E = -1.44269504f;     // -log2(e)

    for (int cc = 0; cc < 4; ++cc) {
#pragma unroll 4
        for (int j = 0; j < 16; ++j) {
            long bE = *(const long*)(gB + j * 1024);          // B frag m=2j
            long bO = *(const long*)(gB + j * 1024 + 512);    // B frag m=2j+1
            long2v a0 = *(const long2v*)(aBase + j * 1024);           // rt0: {m=2j, m=2j+1}
            long2v a1 = *(const long2v*)(aBase + 16384 + j * 1024);   // rt1
            acc0 = __builtin_amdgcn_mfma_f32_32x32x16_fp8_fp8(bE, a0[0], acc0, 0, 0, 0);
            acc1 = __builtin_amdgcn_mfma_f32_32x32x16_fp8_fp8(bE, a1[0], acc1, 0, 0, 0);
            acc0 = __builtin_amdgcn_mfma_f32_32x32x16_fp8_fp8(bO, a0[1], acc0, 0, 0, 0);
            acc1 = __builtin_amdgcn_mfma_f32_32x32x16_fp8_fp8(bO, a1[1], acc1, 0, 0, 0);
        }
        gB += 8 * 16384;                 // uniform bump (SALU)
        // ---- epilogue burst: folded exp (2^(-d*log2e)); d2-keyed argmin ----
        int lc0 = cc * 256 + wlc;
#pragma unroll
        for (int r = 0; r < 16; ++r) {
            int lc = lc0 + (r & 3) + 8 * (r >> 2);
            float cbn = cbL[lc];
            float d2a = fmaxf(fmaf(-2.f, acc0[r], xn0) + cbn, 0.f);
            sv0 += exp2f(fsqrt(d2a) * NL2E);
            km0 = min(km0, (__float_as_uint(d2a) & 0xFFFFF000u) | (unsigned)(cbase + lc));
            float d2b = fmaxf(fmaf(-2.f, acc1[r], xn1) + cbn, 0.f);
            sv1 += exp2f(fsqrt(d2b) * NL2E);
            km1 = min(km1, (__float_as_uint(d2b) & 0xFFFFF000u) | (unsigned)(cbase + lc));
            acc0[r] = 0.f; acc1[r] = 0.f;
        }
    }

    // merge k-halves (lane vs lane+32: same student rows, disjoint cb-col quads)
    sv0 += __shfl_xor(sv0, 32);
    sv1 += __shfl_xor(sv1, 32);
    km0 = min(km0, (unsigned)__shfl_xor((int)km0, 32));
    km1 = min(km1, (unsigned)__shfl_xor((int)km1, 32));
    if (lane < 32) {
        atomicAdd(&s_sum[myrow0], sv0 * __expf(dt0));   // e^dt * sum(e^-d) = sum(e^(dt-d))
        atomicMin(&minpack[myrow0], km0);
        atomicAdd(&s_sum[myrow1], sv1 * __expf(dt1));
        atomicMin(&minpack[myrow1], km1);
    }
}

// ---------------- Kernel 3a: per-token CE/accuracy/emb-loss/target-dist reduce ----------------
__global__ __launch_bounds__(256) void k3a(
    const float* __restrict__ s_sum,
    const unsigned* __restrict__ minpack,
    const int* __restrict__ codes,
    const float* __restrict__ dtg2,
    float* __restrict__ accum)
{
    __shared__ float w0[4], w1[4], w2[4], w3[4];
    int tid = threadIdx.x;
    int n = blockIdx.x * 256 + tid;
    float ce = logf(s_sum[n]);           // = d_t + lse(-d) = per-token CE
    unsigned pred = minpack[n] & 0xFFFu; // col id in the low 12 bits
    float ok = (pred == (unsigned)codes[n]) ? 1.f : 0.f;
    float sq = dtg2[n];
    float td = sqrtf(sq);
#pragma unroll
    for (int m = 1; m < 64; m <<= 1) {
        ce += __shfl_xor(ce, m);
        ok += __shfl_xor(ok, m);
        sq += __shfl_xor(sq, m);
        td += __shfl_xor(td, m);
    }
    int lane = tid & 63, w = tid >> 6;
    if (lane == 0) { w0[w] = ce; w1[w] = ok; w2[w] = sq; w3[w] = td; }
    __syncthreads();
    if (tid == 0) {
        atomicAdd(&accum[0], w0[0] + w0[1] + w0[2] + w0[3]);
        atomicAdd(&accum[1], w1[0] + w1[1] + w1[2] + w1[3]);
        atomicAdd(&accum[2], w2[0] + w2[1] + w2[2] + w2[3]);
        atomicAdd(&accum[3], w3[0] + w3[1] + w3[2] + w3[3]);
    }
}

// ---------------- Kernel 3b: finalize 5 outputs ----------------
__global__ void k3b(const float* __restrict__ accum, float* __restrict__ out)
{
    if (threadIdx.x == 0 && blockIdx.x == 0) {
        float ce   = accum[0] / (float)N_TOK;
        float accy = accum[1] / (float)N_TOK;
        float emb  = accum[2] / ((float)N_TOK * (float)C_);
        float td   = accum[3] / (float)N_TOK;
        out[0] = emb + ce;   // total_loss (EMB_W=CE_W=1)
        out[1] = emb;        // emb_to_codebook_loss
        out[2] = ce;         // ce_loss
        out[3] = accy;       // token_accuracy
        out[4] = td;         // emb_to_target_dist
    }
}

extern "C" void kernel_launch(void* const* d_in, const int* in_sizes, int n_in,
                              void* d_out, int out_size, void* d_ws, size_t ws_size,
                              hipStream_t stream)
{
    const float* student  = (const float*)d_in[0];
    const int*   codes    = (const int*)d_in[1];
    const float* codebook = (const float*)d_in[2];
    // d_in[3] distance_matrix is unused by the reference.
    float* out = (float*)d_out;

    char* ws = (char*)d_ws;
    unsigned char* A8     = (unsigned char*)(ws);                  // 8 MiB
    unsigned char* B8f    = (unsigned char*)(ws + 8388608);        // 2 MiB (fragment-linear)
    float* xnorm          = (float*)(ws + 10485760);               // 64 KiB  ─┐
    float* dtg2           = (float*)(ws + 10551296);               // 64 KiB   │ one zero-memset
    float* s_sum          = (float*)(ws + 10616832);               // 64 KiB   │
    float* accum          = (float*)(ws + 10682368);               // 64 B    ─┘
    unsigned* minpack     = (unsigned*)(ws + 10682624);            // 64 KiB (0xFF memset)
    float* cbnorm         = (float*)(ws + 10748160);               // 16 KiB (fully written by k1)

    hipMemsetAsync(ws + 10485760, 0, 196672, stream);              // xnorm+dtg2+s_sum+accum
    hipMemsetAsync(ws + 10682624, 0xFF, 65536, stream);            // minpack

    // merged prep: blocks 0-511 student transpose/stats, 512-1535 codebook conversion
    hipLaunchKernelGGL(k1_all, dim3(1536), dim3(256), 0, stream,
                       student, codes, codebook, A8, B8f, cbnorm, xnorm, dtg2);
    hipLaunchKernelGGL(k2_main, dim3(1024), dim3(512), 0, stream,
                       A8, B8f, xnorm, dtg2, cbnorm, s_sum, minpack);
    hipLaunchKernelGGL(k3a, dim3(64), dim3(256), 0, stream,
                       s_sum, minpack, codes, dtg2, accum);
    hipLaunchKernelGGL(k3b, dim3(1), dim3(64), 0, stream, accum, out);
}